// Round 2
// baseline (31.962 us; speedup 1.0000x reference)
//
#include <hip/hip_runtime.h>
#include <hip/hip_bf16.h>
#include <math.h>

// BlockwiseDense: y[b,i,j,k] = sum_l quant(relu(cores[i,j,k,l])) * x[b, j*256+l]
// x: (128, 4096) f32, cores: (16,16,256,256) f32, out: (128,16,16,256) f32.
// One WG per (i, j, ns: 64-k slice): grid = 16*16*4 = 1024 WGs, 256 thr, 4 WG/CU.
//
// v2: (1) batched W loads (16 in flight) before quantize — latency hiding;
//     (2) swapped MFMA operands (A=W, B=x) -> f32x4 coalesced stores;
//     (3) paired (lo,hi) level LUT -> single ds_read_b64 gather.

typedef __attribute__((ext_vector_type(4))) float f32x4;
typedef __attribute__((ext_vector_type(2))) float f32x2;
typedef __attribute__((ext_vector_type(8))) short bf16x8;  // 8 bf16 (4 VGPRs)
typedef __attribute__((ext_vector_type(4))) short s16x4;   // 4 bf16 (8B)

#define TAU   0.75f
#define G_INF 2.0f
#define G_MIN 0.001f

__device__ __forceinline__ short f2bf_rne(float f) {
    union { float f; unsigned u; } v; v.f = f;
    unsigned u = v.u;
    return (short)((u + 0x7FFFu + ((u >> 16) & 1u)) >> 16);
}

__device__ __forceinline__ float level_of(float n) {
    // numpy f32 op order: exp((-tau)*n / 255)
    float a = (-TAU) * n;
    a = a / 255.0f;
    float e = expf(a);                       // accurate libm
    float scale = (G_INF - G_MIN) / (1.0f - expf(-TAU));
    return G_MIN + scale * (1.0f - e);
}

__global__ __launch_bounds__(256, 4)
void bd_fused(const float* __restrict__ x,
              const float* __restrict__ cores,
              float* __restrict__ out)
{
    __shared__ f32x2 lut2[256];             // (level[n], level[n+1])
    __shared__ unsigned char wq[64 * 512];  // 64 rows x 256 bf16, XOR-swizzled

    const int tid = threadIdx.x;

    {   // build paired LUT; no cross-thread deps -> single barrier below
        float lo = level_of((float)tid);
        float hi = level_of((float)(tid < 255 ? tid + 1 : 255));
        lut2[tid] = (f32x2){lo, hi};
    }

    const int bid = blockIdx.x;
    const int ns = bid & 3;          // 64-column slice of k
    const int j  = (bid >> 2) & 15;  // input block
    const int i  = bid >> 6;         // output block

    const float scale     = (G_INF - G_MIN) / (1.0f - expf(-TAU));
    const float inv_scale = 1.0f / scale;
    const float kn = -(255.0f / TAU) * 0.69314718055994531f;  // n = kn*log2(t)

    // ---- phase 1: issue ALL W loads (16 x f32x4 in flight per lane) ----
    const float* wsrc = cores + (((size_t)(i * 16 + j)) << 16) + ((size_t)ns << 14);
    f32x4 wv[16];
    #pragma unroll
    for (int it = 0; it < 16; ++it)
        wv[it] = *(const f32x4*)(wsrc + it * 1024 + tid * 4);

    __syncthreads();   // LUT visible before gathers below

    // ---- phase 2: quantize + swizzled LDS write, in arrival order ----
    #pragma unroll
    for (int it = 0; it < 16; ++it) {
        f32x4 v = wv[it];
        s16x4 q;
        #pragma unroll
        for (int c = 0; c < 4; ++c) {
            float w = fmaxf(v[c], 0.0f);
            float t = 1.0f - (w - G_MIN) * inv_scale;  // = exp(-tau*n/255)
            t = fmaxf(t, 1e-20f);
            float nr = kn * __log2f(t);
            int f = (int)floorf(nr);
            f = f < 0 ? 0 : (f > 254 ? 254 : f);
            f32x2 lh = lut2[f];                        // one ds_read_b64 gather
            // off-by-one in f only happens at a level boundary, where both
            // candidate pairs contain the true nearest level -> self-correcting.
            float qv = (w - lh.x < lh.y - w) ? lh.x : lh.y;
            q[c] = f2bf_rne(qv);
        }
        int e  = it * 1024 + tid * 4;
        int r  = e >> 8;                 // local row (k-col of out)
        int kb = (e & 255) * 2;          // byte offset within row (l dim)
        int off = (r * 512 + kb) ^ ((r & 7) << 4);  // bank swizzle
        *(s16x4*)(wq + off) = q;
    }
    __syncthreads();

    // ---- phase 3: MFMA, A = W (rows = k-cols), B = x (cols = batch) ----
    const int wave  = tid >> 6;
    const int lane  = tid & 63;
    const int l15   = lane & 15;
    const int l4    = lane >> 4;
    const int brow0 = wave * 32;

    f32x4 acc[4][2];   // [nt: 16 k-rows][mt: 16 batch-cols]
    #pragma unroll
    for (int nt = 0; nt < 4; ++nt)
        #pragma unroll
        for (int mt = 0; mt < 2; ++mt)
            acc[nt][mt] = (f32x4){0.f, 0.f, 0.f, 0.f};

    // B-fragment source: B[k=l][col=b], lane holds col=lane&15, k=(lane>>4)*8+e
    const float* xb0 = x + (size_t)(brow0 + l15) * 4096 + j * 256 + l4 * 8;

    #pragma unroll
    for (int s = 0; s < 8; ++s) {        // K steps of 32
        bf16x8 bfr[2];
        #pragma unroll
        for (int mt = 0; mt < 2; ++mt) {
            const float* xp = xb0 + mt * (16 * 4096) + s * 32;
            f32x4 v0 = *(const f32x4*)xp;
            f32x4 v1 = *(const f32x4*)(xp + 4);
            bf16x8 b;
            b[0] = f2bf_rne(v0[0]); b[1] = f2bf_rne(v0[1]);
            b[2] = f2bf_rne(v0[2]); b[3] = f2bf_rne(v0[3]);
            b[4] = f2bf_rne(v1[0]); b[5] = f2bf_rne(v1[1]);
            b[6] = f2bf_rne(v1[2]); b[7] = f2bf_rne(v1[3]);
            bfr[mt] = b;
        }
        #pragma unroll
        for (int nt = 0; nt < 4; ++nt) {
            // A-fragment: A[row=n][k], lane holds row=lane&15, k=(lane>>4)*8+e
            int r   = nt * 16 + l15;
            int off = (r * 512 + s * 64 + l4 * 16) ^ ((r & 7) << 4);
            bf16x8 afr = *(const bf16x8*)(wq + off);  // ds_read_b128, swizzled
            acc[nt][0] = __builtin_amdgcn_mfma_f32_16x16x32_bf16(afr, bfr[0], acc[nt][0], 0, 0, 0);
            acc[nt][1] = __builtin_amdgcn_mfma_f32_16x16x32_bf16(afr, bfr[1], acc[nt][1], 0, 0, 0);
        }
    }

    // ---- phase 4: store. D row=(lane>>4)*4+v = k_local, col=lane&15 = b ----
    #pragma unroll
    for (int nt = 0; nt < 4; ++nt) {
        #pragma unroll
        for (int mt = 0; mt < 2; ++mt) {
            int b  = brow0 + mt * 16 + l15;
            int kg = (ns << 6) + nt * 16 + (l4 << 2);
            *(f32x4*)(out + (((size_t)((b * 16 + i) * 16 + j)) << 8) + kg) = acc[nt][mt];
        }
    }
}

extern "C" void kernel_launch(void* const* d_in, const int* in_sizes, int n_in,
                              void* d_out, int out_size, void* d_ws, size_t ws_size,
                              hipStream_t stream) {
    const float* x     = (const float*)d_in[0];
    const float* cores = (const float*)d_in[1];
    float* out = (float*)d_out;
    bd_fused<<<dim3(1024), dim3(256), 0, stream>>>(x, cores, out);
}